// Round 1
// baseline (686.543 us; speedup 1.0000x reference)
//
#include <hip/hip_runtime.h>

#define IN1 128
#define INF 256   // total in feats
#define HID 64

// ---------------- degree / dinv ----------------
__global__ __launch_bounds__(256) void deg_init(float* deg, int N) {
    int i = blockIdx.x * 256 + threadIdx.x;
    if (i < N) deg[i] = 1.0f;
}

__global__ __launch_bounds__(256) void deg_edges(const int* __restrict__ ei, float* deg, int E) {
    int e = blockIdx.x * 256 + threadIdx.x;
    if (e < E) atomicAdd(&deg[ei[E + e]], 1.0f);
}

__global__ __launch_bounds__(256) void dinv_k(float* deg, int N) {
    int i = blockIdx.x * 256 + threadIdx.x;
    if (i < N) deg[i] = rsqrtf(deg[i]);
}

// ---------------- GEMM helpers ----------------
__device__ __forceinline__ void fma_k(const float* Ws, int k, float v, float4 acc[16]) {
    const float4* w = reinterpret_cast<const float4*>(Ws + k * HID);
#pragma unroll
    for (int j = 0; j < 16; ++j) {
        float4 wv = w[j];
        acc[j].x = fmaf(v, wv.x, acc[j].x);
        acc[j].y = fmaf(v, wv.y, acc[j].y);
        acc[j].z = fmaf(v, wv.z, acc[j].z);
        acc[j].w = fmaf(v, wv.w, acc[j].w);
    }
}

// h1 = concat(x, x_da) @ W1      (no bias here)
__global__ __launch_bounds__(256) void gemm1(const float* __restrict__ x,
                                             const float* __restrict__ xda,
                                             const float* __restrict__ W1,
                                             float* __restrict__ h1, int N) {
    __shared__ float Ws[INF * HID];   // 64 KB
    for (int k = threadIdx.x; k < INF * HID; k += 256) Ws[k] = W1[k];
    __syncthreads();
    int n = blockIdx.x * 256 + threadIdx.x;
    if (n >= N) return;
    float4 acc[16];
#pragma unroll
    for (int j = 0; j < 16; ++j) acc[j] = make_float4(0.f, 0.f, 0.f, 0.f);
    const float4* xr = reinterpret_cast<const float4*>(x + (size_t)n * IN1);
    const float4* dr = reinterpret_cast<const float4*>(xda + (size_t)n * IN1);
#pragma unroll 2
    for (int k4 = 0; k4 < 32; ++k4) {
        float4 xv = xr[k4];
        int k = k4 * 4;
        fma_k(Ws, k + 0, xv.x, acc);
        fma_k(Ws, k + 1, xv.y, acc);
        fma_k(Ws, k + 2, xv.z, acc);
        fma_k(Ws, k + 3, xv.w, acc);
    }
#pragma unroll 2
    for (int k4 = 0; k4 < 32; ++k4) {
        float4 xv = dr[k4];
        int k = 128 + k4 * 4;
        fma_k(Ws, k + 0, xv.x, acc);
        fma_k(Ws, k + 1, xv.y, acc);
        fma_k(Ws, k + 2, xv.z, acc);
        fma_k(Ws, k + 3, xv.w, acc);
    }
    float4* o = reinterpret_cast<float4*>(h1 + (size_t)n * HID);
#pragma unroll
    for (int j = 0; j < 16; ++j) o[j] = acc[j];
}

// agg = h * dinv^2 + bias    (full overwrite; zero-init not needed)
__global__ __launch_bounds__(256) void agg_init(const float* __restrict__ h,
                                                const float* __restrict__ dinv,
                                                const float* __restrict__ bias,
                                                float* __restrict__ agg, int N) {
    int t = blockIdx.x * 256 + threadIdx.x;
    int i = t >> 4, c = t & 15;
    if (i >= N) return;
    float di = dinv[i];
    float s = di * di;
    float4 v = reinterpret_cast<const float4*>(h + (size_t)i * HID)[c];
    float4 bv = reinterpret_cast<const float4*>(bias)[c];
    float4 o = make_float4(fmaf(v.x, s, bv.x), fmaf(v.y, s, bv.y),
                           fmaf(v.z, s, bv.z), fmaf(v.w, s, bv.w));
    reinterpret_cast<float4*>(agg + (size_t)i * HID)[c] = o;
}

// agg[dst] += h[src] * dinv[src]*dinv[dst]
__global__ __launch_bounds__(256) void agg_edges(const int* __restrict__ ei,
                                                 const float* __restrict__ h,
                                                 const float* __restrict__ dinv,
                                                 float* agg, int E) {
    int t = blockIdx.x * 256 + threadIdx.x;
    int e = t >> 4, c = t & 15;
    if (e >= E) return;
    int s = ei[e], d = ei[E + e];
    float norm = dinv[s] * dinv[d];
    float4 v = reinterpret_cast<const float4*>(h + (size_t)s * HID)[c];
    float* o = agg + (size_t)d * HID + c * 4;
    atomicAdd(o + 0, v.x * norm);
    atomicAdd(o + 1, v.y * norm);
    atomicAdd(o + 2, v.z * norm);
    atomicAdd(o + 3, v.w * norm);
}

// rb2[b][j] = sum_k relu(x0[root_b][k]) * W2[64+k][j]
__global__ __launch_bounds__(64) void rb2_k(const float* __restrict__ x,
                                            const float* __restrict__ xda,
                                            const int* __restrict__ rootindex,
                                            const float* __restrict__ W2,
                                            float* __restrict__ rb2) {
    int b = blockIdx.x;
    int j = threadIdx.x;          // 64
    int root = rootindex[b];
    const float* xr = x + (size_t)root * IN1;
    const float* dr = xda + (size_t)root * IN1;
    float acc = 0.f;
    for (int k = 0; k < IN1; ++k) {
        float v = fmaxf(xr[k], 0.f);
        acc = fmaf(v, W2[(size_t)(HID + k) * HID + j], acc);
    }
    for (int k = 0; k < IN1; ++k) {
        float v = fmaxf(dr[k], 0.f);
        acc = fmaf(v, W2[(size_t)(HID + IN1 + k) * HID + j], acc);
    }
    rb2[b * HID + j] = acc;
}

// h2 = relu(x2) @ W2[0:64] + rb2[batch]
__global__ __launch_bounds__(256) void gemm2(const float* __restrict__ x2,
                                             const float* __restrict__ W2,
                                             const float* __restrict__ rb2,
                                             const int* __restrict__ batch,
                                             float* __restrict__ h2, int N) {
    __shared__ float Ws[HID * HID];   // 16 KB
    for (int k = threadIdx.x; k < HID * HID; k += 256) Ws[k] = W2[k];
    __syncthreads();
    int n = blockIdx.x * 256 + threadIdx.x;
    if (n >= N) return;
    float4 acc[16];
    int b = batch[n];
    const float4* rv = reinterpret_cast<const float4*>(rb2 + (size_t)b * HID);
#pragma unroll
    for (int j = 0; j < 16; ++j) acc[j] = rv[j];
    const float4* xr = reinterpret_cast<const float4*>(x2 + (size_t)n * HID);
#pragma unroll 2
    for (int k4 = 0; k4 < 16; ++k4) {
        float4 xv = xr[k4];
        xv.x = fmaxf(xv.x, 0.f); xv.y = fmaxf(xv.y, 0.f);
        xv.z = fmaxf(xv.z, 0.f); xv.w = fmaxf(xv.w, 0.f);
        int k = k4 * 4;
        fma_k(Ws, k + 0, xv.x, acc);
        fma_k(Ws, k + 1, xv.y, acc);
        fma_k(Ws, k + 2, xv.z, acc);
        fma_k(Ws, k + 3, xv.w, acc);
    }
    float4* o = reinterpret_cast<float4*>(h2 + (size_t)n * HID);
#pragma unroll
    for (int j = 0; j < 16; ++j) o[j] = acc[j];
}

// segment starts via binary search on sorted batch
__global__ __launch_bounds__(256) void seg_bounds(const int* __restrict__ batch,
                                                  int* __restrict__ segs, int N, int B) {
    int b = blockIdx.x * 256 + threadIdx.x;
    if (b > B) return;
    if (b == B) { segs[B] = N; return; }
    int lo = 0, hi = N;
    while (lo < hi) {
        int mid = (lo + hi) >> 1;
        if (batch[mid] < b) lo = mid + 1; else hi = mid;
    }
    segs[b] = lo;
}

// out[b][0:64] = mean over segment of relu(agg2);  out[b][64:128] = x2[root_b]
__global__ __launch_bounds__(256) void mean_k(const float* __restrict__ agg2,
                                              const float* __restrict__ x2,
                                              const int* __restrict__ segs,
                                              const int* __restrict__ rootindex,
                                              float* __restrict__ out) {
    int b = blockIdx.x;
    int s = segs[b], e = segs[b + 1];
    int f = threadIdx.x & 63;
    int g = threadIdx.x >> 6;    // 0..3
    float p = 0.f;
    for (int i = s + g; i < e; i += 4)
        p += fmaxf(agg2[(size_t)i * HID + f], 0.f);
    __shared__ float red[4][64];
    red[g][f] = p;
    __syncthreads();
    if (g == 0) {
        float tot = red[0][f] + red[1][f] + red[2][f] + red[3][f];
        out[b * 128 + f] = tot / (float)(e - s);
    } else if (g == 1) {
        int root = rootindex[b];
        out[b * 128 + 64 + f] = x2[(size_t)root * HID + f];
    }
}

extern "C" void kernel_launch(void* const* d_in, const int* in_sizes, int n_in,
                              void* d_out, int out_size, void* d_ws, size_t ws_size,
                              hipStream_t stream) {
    const float* x    = (const float*)d_in[0];
    const float* xda  = (const float*)d_in[1];
    const int*   ei   = (const int*)d_in[2];
    const int*   batch= (const int*)d_in[3];
    const int*   root = (const int*)d_in[4];
    const float* W1   = (const float*)d_in[5];
    const float* b1   = (const float*)d_in[6];
    const float* W2   = (const float*)d_in[7];
    const float* b2   = (const float*)d_in[8];
    float* out = (float*)d_out;

    int N = in_sizes[3];
    int E = in_sizes[2] / 2;
    int B = in_sizes[4];

    auto align = [](size_t v) { return (v + 255) & ~(size_t)255; };
    char* w = (char*)d_ws;
    float* dinv = (float*)w;            w += align((size_t)N * 4);
    float* bufA = (float*)w;            w += align((size_t)N * HID * 4);   // h1 then h2
    float* bufB = (float*)w;            w += align((size_t)N * HID * 4);   // x2
    float* bufC = (float*)w;            w += align((size_t)N * HID * 4);   // agg2
    float* rb2  = (float*)w;            w += align((size_t)B * HID * 4);
    int*   segs = (int*)w;              w += align((size_t)(B + 1) * 4);

    int gN   = (N + 255) / 256;
    int gE   = (E + 255) / 256;
    int gN16 = (N * 16 + 255) / 256;
    int gE16 = (E * 16 + 255) / 256;

    deg_init<<<gN, 256, 0, stream>>>(dinv, N);
    deg_edges<<<gE, 256, 0, stream>>>(ei, dinv, E);
    dinv_k<<<gN, 256, 0, stream>>>(dinv, N);

    gemm1<<<gN, 256, 0, stream>>>(x, xda, W1, bufA, N);
    agg_init<<<gN16, 256, 0, stream>>>(bufA, dinv, b1, bufB, N);
    agg_edges<<<gE16, 256, 0, stream>>>(ei, bufA, dinv, bufB, E);   // bufB = x2

    rb2_k<<<B, 64, 0, stream>>>(x, xda, root, W2, rb2);
    gemm2<<<gN, 256, 0, stream>>>(bufB, W2, rb2, batch, bufA, N);   // bufA = h2lin
    agg_init<<<gN16, 256, 0, stream>>>(bufA, dinv, b2, bufC, N);
    agg_edges<<<gE16, 256, 0, stream>>>(ei, bufA, dinv, bufC, E);   // bufC = conv2 pre-relu

    seg_bounds<<<1, 256, 0, stream>>>(batch, segs, N, B);
    mean_k<<<B, 256, 0, stream>>>(bufC, bufB, segs, root, out);
}

// Round 2
// 381.284 us; speedup vs baseline: 1.8006x; 1.8006x over previous
//
#include <hip/hip_runtime.h>

#define IN1 128
#define INF 256   // total in feats
#define HID 64

// ---------------- CSR build ----------------
__global__ __launch_bounds__(256) void zero_counts(int* counts, int N) {
    int i = blockIdx.x * 256 + threadIdx.x;
    if (i < N) counts[i] = 0;
}

__global__ __launch_bounds__(256) void count_edges(const int* __restrict__ ei, int* counts, int E) {
    int e = blockIdx.x * 256 + threadIdx.x;
    if (e < E) atomicAdd(&counts[ei[E + e]], 1);
}

// dinv[i] = rsqrt(indeg + 1)
__global__ __launch_bounds__(256) void dinv_k(const int* __restrict__ counts, float* dinv, int N) {
    int i = blockIdx.x * 256 + threadIdx.x;
    if (i < N) dinv[i] = rsqrtf((float)counts[i] + 1.0f);
}

__global__ __launch_bounds__(256) void block_sums(const int* __restrict__ counts,
                                                  int* __restrict__ bsum, int N) {
    __shared__ int sh[256];
    int i = blockIdx.x * 256 + threadIdx.x;
    sh[threadIdx.x] = (i < N) ? counts[i] : 0;
    __syncthreads();
    for (int off = 128; off > 0; off >>= 1) {
        if (threadIdx.x < off) sh[threadIdx.x] += sh[threadIdx.x + off];
        __syncthreads();
    }
    if (threadIdx.x == 0) bsum[blockIdx.x] = sh[0];
}

// single block, exclusive-scan bsum[nb] -> boff[nb]   (nb <= 512)
__global__ __launch_bounds__(512) void scan_bsums(const int* __restrict__ bsum,
                                                  int* __restrict__ boff, int nb) {
    __shared__ int sh[512];
    int t = threadIdx.x;
    int v = (t < nb) ? bsum[t] : 0;
    sh[t] = v;
    __syncthreads();
    for (int off = 1; off < 512; off <<= 1) {
        int u = (t >= off) ? sh[t - off] : 0;
        __syncthreads();
        sh[t] += u;
        __syncthreads();
    }
    if (t < nb) boff[t] = sh[t] - v;   // exclusive
}

__global__ __launch_bounds__(256) void write_rowstart(const int* __restrict__ counts,
                                                      const int* __restrict__ boff,
                                                      int* __restrict__ rowstart, int N, int E) {
    __shared__ int sh[256];
    int i = blockIdx.x * 256 + threadIdx.x;
    int t = threadIdx.x;
    int v = (i < N) ? counts[i] : 0;
    sh[t] = v;
    __syncthreads();
    for (int off = 1; off < 256; off <<= 1) {
        int u = (t >= off) ? sh[t - off] : 0;
        __syncthreads();
        sh[t] += u;
        __syncthreads();
    }
    if (i < N) rowstart[i] = boff[blockIdx.x] + sh[t] - v;
    if (i == 0) rowstart[N] = E;
}

// counts[] doubles as the fill cursor (destroyed here): fill from the back
__global__ __launch_bounds__(256) void scatter_csr(const int* __restrict__ ei,
                                                   const int* __restrict__ rowstart,
                                                   const float* __restrict__ dinv,
                                                   int* counts,
                                                   int* __restrict__ csr_src,
                                                   float* __restrict__ csr_w, int E) {
    int e = blockIdx.x * 256 + threadIdx.x;
    if (e >= E) return;
    int s = ei[e], d = ei[E + e];
    int pos = rowstart[d] + atomicSub(&counts[d], 1) - 1;
    csr_src[pos] = s;
    csr_w[pos] = dinv[s];
}

// ---------------- GEMM helpers ----------------
__device__ __forceinline__ void fma_k(const float* Ws, int k, float v, float4 acc[16]) {
    const float4* w = reinterpret_cast<const float4*>(Ws + k * HID);
#pragma unroll
    for (int j = 0; j < 16; ++j) {
        float4 wv = w[j];
        acc[j].x = fmaf(v, wv.x, acc[j].x);
        acc[j].y = fmaf(v, wv.y, acc[j].y);
        acc[j].z = fmaf(v, wv.z, acc[j].z);
        acc[j].w = fmaf(v, wv.w, acc[j].w);
    }
}

// h1 = concat(x, x_da) @ W1      (no bias here)
__global__ __launch_bounds__(256) void gemm1(const float* __restrict__ x,
                                             const float* __restrict__ xda,
                                             const float* __restrict__ W1,
                                             float* __restrict__ h1, int N) {
    __shared__ float Ws[INF * HID];   // 64 KB
    for (int k = threadIdx.x; k < INF * HID; k += 256) Ws[k] = W1[k];
    __syncthreads();
    int n = blockIdx.x * 256 + threadIdx.x;
    if (n >= N) return;
    float4 acc[16];
#pragma unroll
    for (int j = 0; j < 16; ++j) acc[j] = make_float4(0.f, 0.f, 0.f, 0.f);
    const float4* xr = reinterpret_cast<const float4*>(x + (size_t)n * IN1);
    const float4* dr = reinterpret_cast<const float4*>(xda + (size_t)n * IN1);
#pragma unroll 2
    for (int k4 = 0; k4 < 32; ++k4) {
        float4 xv = xr[k4];
        int k = k4 * 4;
        fma_k(Ws, k + 0, xv.x, acc);
        fma_k(Ws, k + 1, xv.y, acc);
        fma_k(Ws, k + 2, xv.z, acc);
        fma_k(Ws, k + 3, xv.w, acc);
    }
#pragma unroll 2
    for (int k4 = 0; k4 < 32; ++k4) {
        float4 xv = dr[k4];
        int k = 128 + k4 * 4;
        fma_k(Ws, k + 0, xv.x, acc);
        fma_k(Ws, k + 1, xv.y, acc);
        fma_k(Ws, k + 2, xv.z, acc);
        fma_k(Ws, k + 3, xv.w, acc);
    }
    float4* o = reinterpret_cast<float4*>(h1 + (size_t)n * HID);
#pragma unroll
    for (int j = 0; j < 16; ++j) o[j] = acc[j];
}

// out[i] = h[i]*dinv[i]^2 + bias + sum_{e in CSR(i)} h[src_e] * (csr_w[e]*dinv[i])
__global__ __launch_bounds__(256) void gather(const int* __restrict__ rowstart,
                                              const int* __restrict__ csr_src,
                                              const float* __restrict__ csr_w,
                                              const float* __restrict__ h,
                                              const float* __restrict__ dinv,
                                              const float* __restrict__ bias,
                                              float* __restrict__ out, int N) {
    int t = blockIdx.x * 256 + threadIdx.x;
    int i = t >> 4, c = t & 15;
    if (i >= N) return;
    float di = dinv[i];
    float s2 = di * di;
    float4 v = reinterpret_cast<const float4*>(h + (size_t)i * HID)[c];
    float4 bv = reinterpret_cast<const float4*>(bias)[c];
    float4 acc = make_float4(fmaf(v.x, s2, bv.x), fmaf(v.y, s2, bv.y),
                             fmaf(v.z, s2, bv.z), fmaf(v.w, s2, bv.w));
    int k0 = rowstart[i], k1 = rowstart[i + 1];
    for (int k = k0; k < k1; ++k) {
        int s = csr_src[k];
        float w = csr_w[k] * di;
        float4 hv = reinterpret_cast<const float4*>(h + (size_t)s * HID)[c];
        acc.x = fmaf(hv.x, w, acc.x);
        acc.y = fmaf(hv.y, w, acc.y);
        acc.z = fmaf(hv.z, w, acc.z);
        acc.w = fmaf(hv.w, w, acc.w);
    }
    reinterpret_cast<float4*>(out + (size_t)i * HID)[c] = acc;
}

// rb2[b][j] = sum_k relu(x0[root_b][k]) * W2[64+k][j]
__global__ __launch_bounds__(64) void rb2_k(const float* __restrict__ x,
                                            const float* __restrict__ xda,
                                            const int* __restrict__ rootindex,
                                            const float* __restrict__ W2,
                                            float* __restrict__ rb2) {
    int b = blockIdx.x;
    int j = threadIdx.x;          // 64
    int root = rootindex[b];
    const float* xr = x + (size_t)root * IN1;
    const float* dr = xda + (size_t)root * IN1;
    float acc = 0.f;
    for (int k = 0; k < IN1; ++k) {
        float v = fmaxf(xr[k], 0.f);
        acc = fmaf(v, W2[(size_t)(HID + k) * HID + j], acc);
    }
    for (int k = 0; k < IN1; ++k) {
        float v = fmaxf(dr[k], 0.f);
        acc = fmaf(v, W2[(size_t)(HID + IN1 + k) * HID + j], acc);
    }
    rb2[b * HID + j] = acc;
}

// h2 = relu(x2) @ W2[0:64] + rb2[batch]
__global__ __launch_bounds__(256) void gemm2(const float* __restrict__ x2,
                                             const float* __restrict__ W2,
                                             const float* __restrict__ rb2,
                                             const int* __restrict__ batch,
                                             float* __restrict__ h2, int N) {
    __shared__ float Ws[HID * HID];   // 16 KB
    for (int k = threadIdx.x; k < HID * HID; k += 256) Ws[k] = W2[k];
    __syncthreads();
    int n = blockIdx.x * 256 + threadIdx.x;
    if (n >= N) return;
    float4 acc[16];
    int b = batch[n];
    const float4* rv = reinterpret_cast<const float4*>(rb2 + (size_t)b * HID);
#pragma unroll
    for (int j = 0; j < 16; ++j) acc[j] = rv[j];
    const float4* xr = reinterpret_cast<const float4*>(x2 + (size_t)n * HID);
#pragma unroll 2
    for (int k4 = 0; k4 < 16; ++k4) {
        float4 xv = xr[k4];
        xv.x = fmaxf(xv.x, 0.f); xv.y = fmaxf(xv.y, 0.f);
        xv.z = fmaxf(xv.z, 0.f); xv.w = fmaxf(xv.w, 0.f);
        int k = k4 * 4;
        fma_k(Ws, k + 0, xv.x, acc);
        fma_k(Ws, k + 1, xv.y, acc);
        fma_k(Ws, k + 2, xv.z, acc);
        fma_k(Ws, k + 3, xv.w, acc);
    }
    float4* o = reinterpret_cast<float4*>(h2 + (size_t)n * HID);
#pragma unroll
    for (int j = 0; j < 16; ++j) o[j] = acc[j];
}

// segment starts via binary search on sorted batch
__global__ __launch_bounds__(256) void seg_bounds(const int* __restrict__ batch,
                                                  int* __restrict__ segs, int N, int B) {
    int b = blockIdx.x * 256 + threadIdx.x;
    if (b > B) return;
    if (b == B) { segs[B] = N; return; }
    int lo = 0, hi = N;
    while (lo < hi) {
        int mid = (lo + hi) >> 1;
        if (batch[mid] < b) lo = mid + 1; else hi = mid;
    }
    segs[b] = lo;
}

// out[b][0:64] = mean over segment of relu(agg2);  out[b][64:128] = x2[root_b]
__global__ __launch_bounds__(256) void mean_k(const float* __restrict__ agg2,
                                              const float* __restrict__ x2,
                                              const int* __restrict__ segs,
                                              const int* __restrict__ rootindex,
                                              float* __restrict__ out) {
    int b = blockIdx.x;
    int s = segs[b], e = segs[b + 1];
    int f = threadIdx.x & 63;
    int g = threadIdx.x >> 6;    // 0..3
    float p = 0.f;
    for (int i = s + g; i < e; i += 4)
        p += fmaxf(agg2[(size_t)i * HID + f], 0.f);
    __shared__ float red[4][64];
    red[g][f] = p;
    __syncthreads();
    if (g == 0) {
        float tot = red[0][f] + red[1][f] + red[2][f] + red[3][f];
        out[b * 128 + f] = tot / (float)(e - s);
    } else if (g == 1) {
        int root = rootindex[b];
        out[b * 128 + 64 + f] = x2[(size_t)root * HID + f];
    }
}

extern "C" void kernel_launch(void* const* d_in, const int* in_sizes, int n_in,
                              void* d_out, int out_size, void* d_ws, size_t ws_size,
                              hipStream_t stream) {
    const float* x    = (const float*)d_in[0];
    const float* xda  = (const float*)d_in[1];
    const int*   ei   = (const int*)d_in[2];
    const int*   batch= (const int*)d_in[3];
    const int*   root = (const int*)d_in[4];
    const float* W1   = (const float*)d_in[5];
    const float* b1   = (const float*)d_in[6];
    const float* W2   = (const float*)d_in[7];
    const float* b2   = (const float*)d_in[8];
    float* out = (float*)d_out;

    int N = in_sizes[3];
    int E = in_sizes[2] / 2;
    int B = in_sizes[4];

    int gN  = (N + 255) / 256;     // also = number of scan blocks (nb)
    int gE  = (E + 255) / 256;
    int gN16 = (N * 16 + 255) / 256;
    int nb  = gN;

    auto align = [](size_t v) { return (v + 255) & ~(size_t)255; };
    char* w = (char*)d_ws;
    float* dinv   = (float*)w;  w += align((size_t)N * 4);
    int*   counts = (int*)w;    w += align((size_t)N * 4);
    int*   rowst  = (int*)w;    w += align((size_t)(N + 1) * 4);
    int*   bsum   = (int*)w;    w += align((size_t)nb * 4);
    int*   boff   = (int*)w;    w += align((size_t)nb * 4);
    int*   csr_src= (int*)w;    w += align((size_t)E * 4);
    float* csr_w  = (float*)w;  w += align((size_t)E * 4);
    float* bufA   = (float*)w;  w += align((size_t)N * HID * 4);   // h1 then h2lin
    float* bufB   = (float*)w;  w += align((size_t)N * HID * 4);   // x2
    float* bufC   = (float*)w;  w += align((size_t)N * HID * 4);   // conv2 pre-relu
    float* rb2    = (float*)w;  w += align((size_t)B * HID * 4);
    int*   segs   = (int*)w;    w += align((size_t)(B + 1) * 4);

    // ---- CSR build + dinv ----
    zero_counts<<<gN, 256, 0, stream>>>(counts, N);
    count_edges<<<gE, 256, 0, stream>>>(ei, counts, E);
    dinv_k<<<gN, 256, 0, stream>>>(counts, dinv, N);
    block_sums<<<gN, 256, 0, stream>>>(counts, bsum, N);
    scan_bsums<<<1, 512, 0, stream>>>(bsum, boff, nb);
    write_rowstart<<<gN, 256, 0, stream>>>(counts, boff, rowst, N, E);
    scatter_csr<<<gE, 256, 0, stream>>>(ei, rowst, dinv, counts, csr_src, csr_w, E);

    // ---- layer 1 ----
    gemm1<<<gN, 256, 0, stream>>>(x, xda, W1, bufA, N);
    gather<<<gN16, 256, 0, stream>>>(rowst, csr_src, csr_w, bufA, dinv, b1, bufB, N);  // bufB = x2

    // ---- layer 2 ----
    rb2_k<<<B, 64, 0, stream>>>(x, xda, root, W2, rb2);
    gemm2<<<gN, 256, 0, stream>>>(bufB, W2, rb2, batch, bufA, N);                       // bufA = h2lin
    gather<<<gN16, 256, 0, stream>>>(rowst, csr_src, csr_w, bufA, dinv, b2, bufC, N);  // bufC

    // ---- readout ----
    seg_bounds<<<1, 256, 0, stream>>>(batch, segs, N, B);
    mean_k<<<B, 256, 0, stream>>>(bufC, bufB, segs, root, out);
}

// Round 3
// 314.971 us; speedup vs baseline: 2.1797x; 1.2105x over previous
//
#include <hip/hip_runtime.h>

#define IN1 128
#define K1 256
#define HID 64

typedef __attribute__((ext_vector_type(8))) __bf16 bf16x8;
typedef __attribute__((ext_vector_type(4))) float f32x4;

// swizzled LDS element index: XOR row-low-bits into the 16B-slot bits so a
// wave's 16-row x 4-kgroup ds_read_b128 pattern is balanced across banks
__device__ __forceinline__ int swz(int row, int k, int ldk) {
    return (row * ldk + k) ^ ((row & 7) << 3);
}

// ---------------- CSR build ----------------
__global__ __launch_bounds__(256) void zero_counts(int* counts, int N) {
    int i = blockIdx.x * 256 + threadIdx.x;
    if (i < N) counts[i] = 0;
}

__global__ __launch_bounds__(256) void count_edges(const int* __restrict__ ei, int* counts, int E) {
    int e = blockIdx.x * 256 + threadIdx.x;
    if (e < E) atomicAdd(&counts[ei[E + e]], 1);
}

__global__ __launch_bounds__(256) void dinv_k(const int* __restrict__ counts, float* dinv, int N) {
    int i = blockIdx.x * 256 + threadIdx.x;
    if (i < N) dinv[i] = rsqrtf((float)counts[i] + 1.0f);
}

__global__ __launch_bounds__(256) void block_sums(const int* __restrict__ counts,
                                                  int* __restrict__ bsum, int N) {
    __shared__ int sh[256];
    int i = blockIdx.x * 256 + threadIdx.x;
    sh[threadIdx.x] = (i < N) ? counts[i] : 0;
    __syncthreads();
    for (int off = 128; off > 0; off >>= 1) {
        if (threadIdx.x < off) sh[threadIdx.x] += sh[threadIdx.x + off];
        __syncthreads();
    }
    if (threadIdx.x == 0) bsum[blockIdx.x] = sh[0];
}

__global__ __launch_bounds__(512) void scan_bsums(const int* __restrict__ bsum,
                                                  int* __restrict__ boff, int nb) {
    __shared__ int sh[512];
    int t = threadIdx.x;
    int v = (t < nb) ? bsum[t] : 0;
    sh[t] = v;
    __syncthreads();
    for (int off = 1; off < 512; off <<= 1) {
        int u = (t >= off) ? sh[t - off] : 0;
        __syncthreads();
        sh[t] += u;
        __syncthreads();
    }
    if (t < nb) boff[t] = sh[t] - v;   // exclusive
}

__global__ __launch_bounds__(256) void write_rowstart(const int* __restrict__ counts,
                                                      const int* __restrict__ boff,
                                                      int* __restrict__ rowstart, int N, int E) {
    __shared__ int sh[256];
    int i = blockIdx.x * 256 + threadIdx.x;
    int t = threadIdx.x;
    int v = (i < N) ? counts[i] : 0;
    sh[t] = v;
    __syncthreads();
    for (int off = 1; off < 256; off <<= 1) {
        int u = (t >= off) ? sh[t - off] : 0;
        __syncthreads();
        sh[t] += u;
        __syncthreads();
    }
    if (i < N) rowstart[i] = boff[blockIdx.x] + sh[t] - v;
    if (i == 0) rowstart[N] = E;
}

__global__ __launch_bounds__(256) void scatter_csr(const int* __restrict__ ei,
                                                   const int* __restrict__ rowstart,
                                                   const float* __restrict__ dinv,
                                                   int* counts,
                                                   int* __restrict__ csr_src,
                                                   float* __restrict__ csr_w, int E) {
    int e = blockIdx.x * 256 + threadIdx.x;
    if (e >= E) return;
    int s = ei[e], d = ei[E + e];
    int pos = rowstart[d] + atomicSub(&counts[d], 1) - 1;
    csr_src[pos] = s;
    csr_w[pos] = dinv[s];
}

// ---------------- MFMA GEMM 1: h1 = concat(x,xda) @ W1 ----------------
// block: 64 output rows x 64 cols, 4 waves (wave w = rows w*16..w*16+15)
__global__ __launch_bounds__(256) void gemm1_mfma(const float* __restrict__ x,
                                                  const float* __restrict__ xda,
                                                  const float* __restrict__ W1,
                                                  float* __restrict__ h1, int N) {
    __shared__ __bf16 As[64 * K1];   // 32 KB, row-major [row][k], swizzled
    __shared__ __bf16 Ws[64 * K1];   // 32 KB, transposed [n][k], swizzled
    int tid = threadIdx.x;
    int row0 = blockIdx.x * 64;

    // stage Wt: W1[k][n] -> Ws[n][k]   (coalesced global read, scalar LDS write)
    for (int e = tid; e < 64 * K1; e += 256) {
        int k = e >> 6, n = e & 63;
        Ws[swz(n, k, K1)] = (__bf16)W1[e];
    }
    // stage A tile with fp32->bf16 conversion (8 elements per thread per iter)
    for (int g = tid; g < 64 * 32; g += 256) {
        int r = g >> 5, kg = g & 31;
        int row = row0 + r;
        int k8 = kg * 8;
        float f[8];
        if (row < N) {
            const float* src = (k8 < IN1) ? (x + (size_t)row * IN1 + k8)
                                          : (xda + (size_t)row * IN1 + (k8 - IN1));
            float4 a = reinterpret_cast<const float4*>(src)[0];
            float4 b = reinterpret_cast<const float4*>(src)[1];
            f[0] = a.x; f[1] = a.y; f[2] = a.z; f[3] = a.w;
            f[4] = b.x; f[5] = b.y; f[6] = b.z; f[7] = b.w;
        } else {
#pragma unroll
            for (int i = 0; i < 8; ++i) f[i] = 0.f;
        }
        bf16x8 p;
#pragma unroll
        for (int i = 0; i < 8; ++i) p[i] = (__bf16)f[i];
        *reinterpret_cast<bf16x8*>(&As[swz(r, k8, K1)]) = p;
    }
    __syncthreads();

    int w = tid >> 6, l = tid & 63;
    int lr = l & 15, lg = l >> 4;
    f32x4 acc[4] = {};
    int arow = w * 16 + lr;
#pragma unroll
    for (int t = 0; t < 8; ++t) {
        int k0 = t * 32 + lg * 8;
        bf16x8 af = *reinterpret_cast<const bf16x8*>(&As[swz(arow, k0, K1)]);
#pragma unroll
        for (int c = 0; c < 4; ++c) {
            bf16x8 bfr = *reinterpret_cast<const bf16x8*>(&Ws[swz(c * 16 + lr, k0, K1)]);
            acc[c] = __builtin_amdgcn_mfma_f32_16x16x32_bf16(af, bfr, acc[c], 0, 0, 0);
        }
    }
    // C layout: col = lane&15, row = (lane>>4)*4 + reg
#pragma unroll
    for (int c = 0; c < 4; ++c) {
#pragma unroll
        for (int r = 0; r < 4; ++r) {
            int row = row0 + w * 16 + lg * 4 + r;
            if (row < N) h1[(size_t)row * HID + c * 16 + lr] = acc[c][r];
        }
    }
}

// ---------------- MFMA GEMM 2: h2 = relu(x2) @ W2[0:64] + rb2[batch] ----------------
__global__ __launch_bounds__(256) void gemm2_mfma(const float* __restrict__ x2,
                                                  const float* __restrict__ W2,
                                                  const float* __restrict__ rb2,
                                                  const int* __restrict__ batch,
                                                  float* __restrict__ h2, int N) {
    __shared__ __bf16 As[64 * 64];   // 8 KB
    __shared__ __bf16 Ws[64 * 64];   // 8 KB
    int tid = threadIdx.x;
    int row0 = blockIdx.x * 64;

    for (int e = tid; e < 64 * 64; e += 256) {
        int k = e >> 6, n = e & 63;
        Ws[swz(n, k, 64)] = (__bf16)W2[e];   // first 64 rows of W2
    }
    for (int g = tid; g < 64 * 8; g += 256) {
        int r = g >> 3, kg = g & 7;
        int row = row0 + r;
        int k8 = kg * 8;
        float f[8];
        if (row < N) {
            const float* src = x2 + (size_t)row * 64 + k8;
            float4 a = reinterpret_cast<const float4*>(src)[0];
            float4 b = reinterpret_cast<const float4*>(src)[1];
            f[0] = a.x; f[1] = a.y; f[2] = a.z; f[3] = a.w;
            f[4] = b.x; f[5] = b.y; f[6] = b.z; f[7] = b.w;
        } else {
#pragma unroll
            for (int i = 0; i < 8; ++i) f[i] = 0.f;
        }
        bf16x8 p;
#pragma unroll
        for (int i = 0; i < 8; ++i) p[i] = (__bf16)fmaxf(f[i], 0.f);   // fused relu
        *reinterpret_cast<bf16x8*>(&As[swz(r, k8, 64)]) = p;
    }
    __syncthreads();

    int w = tid >> 6, l = tid & 63;
    int lr = l & 15, lg = l >> 4;
    f32x4 acc[4] = {};
    int arow = w * 16 + lr;
#pragma unroll
    for (int t = 0; t < 2; ++t) {
        int k0 = t * 32 + lg * 8;
        bf16x8 af = *reinterpret_cast<const bf16x8*>(&As[swz(arow, k0, 64)]);
#pragma unroll
        for (int c = 0; c < 4; ++c) {
            bf16x8 bfr = *reinterpret_cast<const bf16x8*>(&Ws[swz(c * 16 + lr, k0, 64)]);
            acc[c] = __builtin_amdgcn_mfma_f32_16x16x32_bf16(af, bfr, acc[c], 0, 0, 0);
        }
    }
#pragma unroll
    for (int r = 0; r < 4; ++r) {
        int row = row0 + w * 16 + lg * 4 + r;
        if (row >= N) continue;
        int b = batch[row];
        const float* rv = rb2 + (size_t)b * HID;
#pragma unroll
        for (int c = 0; c < 4; ++c)
            h2[(size_t)row * HID + c * 16 + lr] = acc[c][r] + rv[c * 16 + lr];
    }
}

// ---------------- gather (unchanged) ----------------
__global__ __launch_bounds__(256) void gather(const int* __restrict__ rowstart,
                                              const int* __restrict__ csr_src,
                                              const float* __restrict__ csr_w,
                                              const float* __restrict__ h,
                                              const float* __restrict__ dinv,
                                              const float* __restrict__ bias,
                                              float* __restrict__ out, int N) {
    int t = blockIdx.x * 256 + threadIdx.x;
    int i = t >> 4, c = t & 15;
    if (i >= N) return;
    float di = dinv[i];
    float s2 = di * di;
    float4 v = reinterpret_cast<const float4*>(h + (size_t)i * HID)[c];
    float4 bv = reinterpret_cast<const float4*>(bias)[c];
    float4 acc = make_float4(fmaf(v.x, s2, bv.x), fmaf(v.y, s2, bv.y),
                             fmaf(v.z, s2, bv.z), fmaf(v.w, s2, bv.w));
    int k0 = rowstart[i], k1 = rowstart[i + 1];
    for (int k = k0; k < k1; ++k) {
        int s = csr_src[k];
        float w = csr_w[k] * di;
        float4 hv = reinterpret_cast<const float4*>(h + (size_t)s * HID)[c];
        acc.x = fmaf(hv.x, w, acc.x);
        acc.y = fmaf(hv.y, w, acc.y);
        acc.z = fmaf(hv.z, w, acc.z);
        acc.w = fmaf(hv.w, w, acc.w);
    }
    reinterpret_cast<float4*>(out + (size_t)i * HID)[c] = acc;
}

// rb2[b][j] = sum_k relu(x0[root_b][k]) * W2[64+k][j]
__global__ __launch_bounds__(64) void rb2_k(const float* __restrict__ x,
                                            const float* __restrict__ xda,
                                            const int* __restrict__ rootindex,
                                            const float* __restrict__ W2,
                                            float* __restrict__ rb2) {
    int b = blockIdx.x;
    int j = threadIdx.x;
    int root = rootindex[b];
    const float* xr = x + (size_t)root * IN1;
    const float* dr = xda + (size_t)root * IN1;
    float acc = 0.f;
    for (int k = 0; k < IN1; ++k) {
        float v = fmaxf(xr[k], 0.f);
        acc = fmaf(v, W2[(size_t)(HID + k) * HID + j], acc);
    }
    for (int k = 0; k < IN1; ++k) {
        float v = fmaxf(dr[k], 0.f);
        acc = fmaf(v, W2[(size_t)(HID + IN1 + k) * HID + j], acc);
    }
    rb2[b * HID + j] = acc;
}

__global__ __launch_bounds__(256) void seg_bounds(const int* __restrict__ batch,
                                                  int* __restrict__ segs, int N, int B) {
    int b = blockIdx.x * 256 + threadIdx.x;
    if (b > B) return;
    if (b == B) { segs[B] = N; return; }
    int lo = 0, hi = N;
    while (lo < hi) {
        int mid = (lo + hi) >> 1;
        if (batch[mid] < b) lo = mid + 1; else hi = mid;
    }
    segs[b] = lo;
}

__global__ __launch_bounds__(256) void mean_k(const float* __restrict__ agg2,
                                              const float* __restrict__ x2,
                                              const int* __restrict__ segs,
                                              const int* __restrict__ rootindex,
                                              float* __restrict__ out) {
    int b = blockIdx.x;
    int s = segs[b], e = segs[b + 1];
    int f = threadIdx.x & 63;
    int g = threadIdx.x >> 6;
    float p = 0.f;
    for (int i = s + g; i < e; i += 4)
        p += fmaxf(agg2[(size_t)i * HID + f], 0.f);
    __shared__ float red[4][64];
    red[g][f] = p;
    __syncthreads();
    if (g == 0) {
        float tot = red[0][f] + red[1][f] + red[2][f] + red[3][f];
        out[b * 128 + f] = tot / (float)(e - s);
    } else if (g == 1) {
        int root = rootindex[b];
        out[b * 128 + 64 + f] = x2[(size_t)root * HID + f];
    }
}

extern "C" void kernel_launch(void* const* d_in, const int* in_sizes, int n_in,
                              void* d_out, int out_size, void* d_ws, size_t ws_size,
                              hipStream_t stream) {
    const float* x    = (const float*)d_in[0];
    const float* xda  = (const float*)d_in[1];
    const int*   ei   = (const int*)d_in[2];
    const int*   batch= (const int*)d_in[3];
    const int*   root = (const int*)d_in[4];
    const float* W1   = (const float*)d_in[5];
    const float* b1   = (const float*)d_in[6];
    const float* W2   = (const float*)d_in[7];
    const float* b2   = (const float*)d_in[8];
    float* out = (float*)d_out;

    int N = in_sizes[3];
    int E = in_sizes[2] / 2;
    int B = in_sizes[4];

    int gN   = (N + 255) / 256;
    int gE   = (E + 255) / 256;
    int gN16 = (N * 16 + 255) / 256;
    int gM   = (N + 63) / 64;     // MFMA gemm blocks
    int nb   = gN;

    auto align = [](size_t v) { return (v + 255) & ~(size_t)255; };
    char* w = (char*)d_ws;
    float* dinv   = (float*)w;  w += align((size_t)N * 4);
    int*   counts = (int*)w;    w += align((size_t)N * 4);
    int*   rowst  = (int*)w;    w += align((size_t)(N + 1) * 4);
    int*   bsum   = (int*)w;    w += align((size_t)nb * 4);
    int*   boff   = (int*)w;    w += align((size_t)nb * 4);
    int*   csr_src= (int*)w;    w += align((size_t)E * 4);
    float* csr_w  = (float*)w;  w += align((size_t)E * 4);
    float* bufA   = (float*)w;  w += align((size_t)N * HID * 4);   // h1 then h2lin
    float* bufB   = (float*)w;  w += align((size_t)N * HID * 4);   // x2
    float* bufC   = (float*)w;  w += align((size_t)N * HID * 4);   // conv2 pre-relu
    float* rb2    = (float*)w;  w += align((size_t)B * HID * 4);
    int*   segs   = (int*)w;    w += align((size_t)(B + 1) * 4);

    // ---- CSR build + dinv ----
    zero_counts<<<gN, 256, 0, stream>>>(counts, N);
    count_edges<<<gE, 256, 0, stream>>>(ei, counts, E);
    dinv_k<<<gN, 256, 0, stream>>>(counts, dinv, N);
    block_sums<<<gN, 256, 0, stream>>>(counts, bsum, N);
    scan_bsums<<<1, 512, 0, stream>>>(bsum, boff, nb);
    write_rowstart<<<gN, 256, 0, stream>>>(counts, boff, rowst, N, E);
    scatter_csr<<<gE, 256, 0, stream>>>(ei, rowst, dinv, counts, csr_src, csr_w, E);

    // ---- layer 1 ----
    gemm1_mfma<<<gM, 256, 0, stream>>>(x, xda, W1, bufA, N);
    gather<<<gN16, 256, 0, stream>>>(rowst, csr_src, csr_w, bufA, dinv, b1, bufB, N);  // bufB = x2

    // ---- layer 2 ----
    rb2_k<<<B, 64, 0, stream>>>(x, xda, root, W2, rb2);
    gemm2_mfma<<<gM, 256, 0, stream>>>(bufB, W2, rb2, batch, bufA, N);                 // bufA = h2lin
    gather<<<gN16, 256, 0, stream>>>(rowst, csr_src, csr_w, bufA, dinv, b2, bufC, N);

    // ---- readout ----
    seg_bounds<<<1, 256, 0, stream>>>(batch, segs, N, B);
    mean_k<<<B, 256, 0, stream>>>(bufC, bufB, segs, root, out);
}

// Round 4
// 256.868 us; speedup vs baseline: 2.6727x; 1.2262x over previous
//
#include <hip/hip_runtime.h>

#define IN1 128
#define K1 256
#define HID 64
#define MCH 16   // mean-reduction chunks per graph

typedef __attribute__((ext_vector_type(8))) __bf16 bf16x8;
typedef __attribute__((ext_vector_type(4))) float f32x4;

// swizzled LDS/element index: XOR row-low-bits into 16B-slot bits
__device__ __forceinline__ int swz(int row, int k, int ldk) {
    return (row * ldk + k) ^ ((row & 7) << 3);
}

// ---------------- CSR build ----------------
__global__ __launch_bounds__(256) void zero_counts(int* counts, int N) {
    int i = blockIdx.x * 256 + threadIdx.x;
    if (i < N) counts[i] = 0;
}

__global__ __launch_bounds__(256) void count_edges(const int* __restrict__ ei, int* counts, int E) {
    int e = blockIdx.x * 256 + threadIdx.x;
    if (e < E) atomicAdd(&counts[ei[E + e]], 1);
}

__global__ __launch_bounds__(256) void dinv_k(const int* __restrict__ counts, float* dinv, int N) {
    int i = blockIdx.x * 256 + threadIdx.x;
    if (i < N) dinv[i] = rsqrtf((float)counts[i] + 1.0f);
}

__global__ __launch_bounds__(256) void block_sums(const int* __restrict__ counts,
                                                  int* __restrict__ bsum, int N) {
    __shared__ int sh[256];
    int i = blockIdx.x * 256 + threadIdx.x;
    sh[threadIdx.x] = (i < N) ? counts[i] : 0;
    __syncthreads();
    for (int off = 128; off > 0; off >>= 1) {
        if (threadIdx.x < off) sh[threadIdx.x] += sh[threadIdx.x + off];
        __syncthreads();
    }
    if (threadIdx.x == 0) bsum[blockIdx.x] = sh[0];
}

__global__ __launch_bounds__(512) void scan_bsums(const int* __restrict__ bsum,
                                                  int* __restrict__ boff, int nb) {
    __shared__ int sh[512];
    int t = threadIdx.x;
    int v = (t < nb) ? bsum[t] : 0;
    sh[t] = v;
    __syncthreads();
    for (int off = 1; off < 512; off <<= 1) {
        int u = (t >= off) ? sh[t - off] : 0;
        __syncthreads();
        sh[t] += u;
        __syncthreads();
    }
    if (t < nb) boff[t] = sh[t] - v;   // exclusive
}

__global__ __launch_bounds__(256) void write_rowstart(const int* __restrict__ counts,
                                                      const int* __restrict__ boff,
                                                      int* __restrict__ rowstart, int N, int E) {
    __shared__ int sh[256];
    int i = blockIdx.x * 256 + threadIdx.x;
    int t = threadIdx.x;
    int v = (i < N) ? counts[i] : 0;
    sh[t] = v;
    __syncthreads();
    for (int off = 1; off < 256; off <<= 1) {
        int u = (t >= off) ? sh[t - off] : 0;
        __syncthreads();
        sh[t] += u;
        __syncthreads();
    }
    if (i < N) rowstart[i] = boff[blockIdx.x] + sh[t] - v;
    if (i == 0) rowstart[N] = E;
}

__global__ __launch_bounds__(256) void scatter_csr(const int* __restrict__ ei,
                                                   const int* __restrict__ rowstart,
                                                   const float* __restrict__ dinv,
                                                   int* counts,
                                                   int* __restrict__ csr_src,
                                                   float* __restrict__ csr_w, int E) {
    int e = blockIdx.x * 256 + threadIdx.x;
    if (e >= E) return;
    int s = ei[e], d = ei[E + e];
    int pos = rowstart[d] + atomicSub(&counts[d], 1) - 1;
    csr_src[pos] = s;
    csr_w[pos] = dinv[s];
}

// ---------------- W prep: bf16, transposed, pre-swizzled images ----------------
__global__ __launch_bounds__(256) void prep_w(const float* __restrict__ W1,
                                              const float* __restrict__ W2,
                                              __bf16* __restrict__ w1img,
                                              __bf16* __restrict__ w2img) {
    int tid = blockIdx.x * 256 + threadIdx.x;
    if (tid < 64 * K1) {
        int k = tid >> 6, n = tid & 63;
        w1img[swz(n, k, K1)] = (__bf16)W1[tid];
    } else if (tid < 64 * K1 + 64 * 64) {
        int e = tid - 64 * K1;
        int k = e >> 6, n = e & 63;
        w2img[swz(n, k, 64)] = (__bf16)W2[e];
    }
}

// ---------------- MFMA GEMM 1: h1 = concat(x,xda) @ W1 ----------------
// 64 rows x 64 cols per block, 4 waves; W in LDS (vector-staged from image),
// A fragments loaded directly from global with inline fp32->bf16.
__global__ __launch_bounds__(256) void gemm1_mfma(const float* __restrict__ x,
                                                  const float* __restrict__ xda,
                                                  const __bf16* __restrict__ w1img,
                                                  float* __restrict__ h1, int N) {
    __shared__ __bf16 Ws[64 * K1];   // 32 KB, already-swizzled image
    int tid = threadIdx.x;
#pragma unroll
    for (int i = 0; i < 8; ++i)
        reinterpret_cast<bf16x8*>(Ws)[i * 256 + tid] =
            reinterpret_cast<const bf16x8*>(w1img)[i * 256 + tid];
    __syncthreads();

    int row0 = blockIdx.x * 64;
    int w = tid >> 6, l = tid & 63;
    int lr = l & 15, lg = l >> 4;
    int arow = row0 + w * 16 + lr;
    bool rowok = arow < N;
    const float4* a0 = reinterpret_cast<const float4*>(x + (size_t)arow * IN1);
    const float4* a1 = reinterpret_cast<const float4*>(xda + (size_t)arow * IN1);
    f32x4 acc[4] = {};
#pragma unroll
    for (int t = 0; t < 8; ++t) {
        int k0 = t * 32 + lg * 8;
        float4 fa = make_float4(0.f, 0.f, 0.f, 0.f), fb = fa;
        if (rowok) {
            const float4* src = (t < 4) ? (a0 + (k0 >> 2)) : (a1 + ((k0 - 128) >> 2));
            fa = src[0];
            fb = src[1];
        }
        bf16x8 af;
        af[0] = (__bf16)fa.x; af[1] = (__bf16)fa.y; af[2] = (__bf16)fa.z; af[3] = (__bf16)fa.w;
        af[4] = (__bf16)fb.x; af[5] = (__bf16)fb.y; af[6] = (__bf16)fb.z; af[7] = (__bf16)fb.w;
#pragma unroll
        for (int c = 0; c < 4; ++c) {
            bf16x8 bfr = *reinterpret_cast<const bf16x8*>(&Ws[swz(c * 16 + lr, k0, K1)]);
            acc[c] = __builtin_amdgcn_mfma_f32_16x16x32_bf16(af, bfr, acc[c], 0, 0, 0);
        }
    }
    // C layout: col = lane&15, row = (lane>>4)*4 + reg
#pragma unroll
    for (int c = 0; c < 4; ++c) {
#pragma unroll
        for (int r = 0; r < 4; ++r) {
            int row = row0 + w * 16 + lg * 4 + r;
            if (row < N) h1[(size_t)row * HID + c * 16 + lr] = acc[c][r];
        }
    }
}

// ---------------- MFMA GEMM 2: h2 = relu(x2) @ W2[0:64] + rb2[batch] ----------------
__global__ __launch_bounds__(256) void gemm2_mfma(const float* __restrict__ x2,
                                                  const __bf16* __restrict__ w2img,
                                                  const float* __restrict__ rb2,
                                                  const int* __restrict__ batch,
                                                  float* __restrict__ h2, int N) {
    __shared__ __bf16 Ws[64 * 64];   // 8 KB
    int tid = threadIdx.x;
#pragma unroll
    for (int i = 0; i < 2; ++i)
        reinterpret_cast<bf16x8*>(Ws)[i * 256 + tid] =
            reinterpret_cast<const bf16x8*>(w2img)[i * 256 + tid];
    __syncthreads();

    int row0 = blockIdx.x * 64;
    int w = tid >> 6, l = tid & 63;
    int lr = l & 15, lg = l >> 4;
    int arow = row0 + w * 16 + lr;
    bool rowok = arow < N;
    const float4* a0 = reinterpret_cast<const float4*>(x2 + (size_t)arow * HID);
    f32x4 acc[4] = {};
#pragma unroll
    for (int t = 0; t < 2; ++t) {
        int k0 = t * 32 + lg * 8;
        float4 fa = make_float4(0.f, 0.f, 0.f, 0.f), fb = fa;
        if (rowok) {
            fa = a0[k0 >> 2];
            fb = a0[(k0 >> 2) + 1];
        }
        bf16x8 af;
        af[0] = (__bf16)fmaxf(fa.x, 0.f); af[1] = (__bf16)fmaxf(fa.y, 0.f);
        af[2] = (__bf16)fmaxf(fa.z, 0.f); af[3] = (__bf16)fmaxf(fa.w, 0.f);
        af[4] = (__bf16)fmaxf(fb.x, 0.f); af[5] = (__bf16)fmaxf(fb.y, 0.f);
        af[6] = (__bf16)fmaxf(fb.z, 0.f); af[7] = (__bf16)fmaxf(fb.w, 0.f);
#pragma unroll
        for (int c = 0; c < 4; ++c) {
            bf16x8 bfr = *reinterpret_cast<const bf16x8*>(&Ws[swz(c * 16 + lr, k0, 64)]);
            acc[c] = __builtin_amdgcn_mfma_f32_16x16x32_bf16(af, bfr, acc[c], 0, 0, 0);
        }
    }
#pragma unroll
    for (int r = 0; r < 4; ++r) {
        int row = row0 + w * 16 + lg * 4 + r;
        if (row >= N) continue;
        int b = batch[row];
        const float* rv = rb2 + (size_t)b * HID;
#pragma unroll
        for (int c = 0; c < 4; ++c)
            h2[(size_t)row * HID + c * 16 + lr] = acc[c][r] + rv[c * 16 + lr];
    }
}

// ---------------- gather (unchanged) ----------------
__global__ __launch_bounds__(256) void gather(const int* __restrict__ rowstart,
                                              const int* __restrict__ csr_src,
                                              const float* __restrict__ csr_w,
                                              const float* __restrict__ h,
                                              const float* __restrict__ dinv,
                                              const float* __restrict__ bias,
                                              float* __restrict__ out, int N) {
    int t = blockIdx.x * 256 + threadIdx.x;
    int i = t >> 4, c = t & 15;
    if (i >= N) return;
    float di = dinv[i];
    float s2 = di * di;
    float4 v = reinterpret_cast<const float4*>(h + (size_t)i * HID)[c];
    float4 bv = reinterpret_cast<const float4*>(bias)[c];
    float4 acc = make_float4(fmaf(v.x, s2, bv.x), fmaf(v.y, s2, bv.y),
                             fmaf(v.z, s2, bv.z), fmaf(v.w, s2, bv.w));
    int k0 = rowstart[i], k1 = rowstart[i + 1];
    for (int k = k0; k < k1; ++k) {
        int s = csr_src[k];
        float w = csr_w[k] * di;
        float4 hv = reinterpret_cast<const float4*>(h + (size_t)s * HID)[c];
        acc.x = fmaf(hv.x, w, acc.x);
        acc.y = fmaf(hv.y, w, acc.y);
        acc.z = fmaf(hv.z, w, acc.z);
        acc.w = fmaf(hv.w, w, acc.w);
    }
    reinterpret_cast<float4*>(out + (size_t)i * HID)[c] = acc;
}

// rb2[b][j] = sum_k relu(x0[root_b][k]) * W2[64+k][j]
__global__ __launch_bounds__(64) void rb2_k(const float* __restrict__ x,
                                            const float* __restrict__ xda,
                                            const int* __restrict__ rootindex,
                                            const float* __restrict__ W2,
                                            float* __restrict__ rb2) {
    int b = blockIdx.x;
    int j = threadIdx.x;
    int root = rootindex[b];
    const float* xr = x + (size_t)root * IN1;
    const float* dr = xda + (size_t)root * IN1;
    float acc = 0.f;
    for (int k = 0; k < IN1; ++k) {
        float v = fmaxf(xr[k], 0.f);
        acc = fmaf(v, W2[(size_t)(HID + k) * HID + j], acc);
    }
    for (int k = 0; k < IN1; ++k) {
        float v = fmaxf(dr[k], 0.f);
        acc = fmaf(v, W2[(size_t)(HID + IN1 + k) * HID + j], acc);
    }
    rb2[b * HID + j] = acc;
}

__global__ __launch_bounds__(256) void seg_bounds(const int* __restrict__ batch,
                                                  int* __restrict__ segs, int N, int B) {
    int b = blockIdx.x * 256 + threadIdx.x;
    if (b > B) return;
    if (b == B) { segs[B] = N; return; }
    int lo = 0, hi = N;
    while (lo < hi) {
        int mid = (lo + hi) >> 1;
        if (batch[mid] < b) lo = mid + 1; else hi = mid;
    }
    segs[b] = lo;
}

// ---------------- mean: two-stage ----------------
__global__ __launch_bounds__(256) void mean_part(const float* __restrict__ agg2,
                                                 const int* __restrict__ segs,
                                                 float* __restrict__ part) {
    int b = blockIdx.x / MCH, c = blockIdx.x % MCH;
    int s = segs[b], e = segs[b + 1];
    long len = e - s;
    int cs = s + (int)(len * c / MCH);
    int ce = s + (int)(len * (c + 1) / MCH);
    int f = threadIdx.x & 63, g = threadIdx.x >> 6;
    float p = 0.f;
    for (int i = cs + g; i < ce; i += 4)
        p += fmaxf(agg2[(size_t)i * HID + f], 0.f);
    __shared__ float red[4][64];
    red[g][f] = p;
    __syncthreads();
    if (g == 0)
        part[((size_t)b * MCH + c) * 64 + f] = red[0][f] + red[1][f] + red[2][f] + red[3][f];
}

__global__ __launch_bounds__(128) void mean_fin(const float* __restrict__ part,
                                                const float* __restrict__ x2,
                                                const int* __restrict__ segs,
                                                const int* __restrict__ rootindex,
                                                float* __restrict__ out) {
    int b = blockIdx.x;
    int f = threadIdx.x;   // 0..127
    if (f < 64) {
        float s = 0.f;
#pragma unroll
        for (int c = 0; c < MCH; ++c) s += part[((size_t)b * MCH + c) * 64 + f];
        out[b * 128 + f] = s / (float)(segs[b + 1] - segs[b]);
    } else {
        int root = rootindex[b];
        out[b * 128 + f] = x2[(size_t)root * HID + (f - 64)];
    }
}

extern "C" void kernel_launch(void* const* d_in, const int* in_sizes, int n_in,
                              void* d_out, int out_size, void* d_ws, size_t ws_size,
                              hipStream_t stream) {
    const float* x    = (const float*)d_in[0];
    const float* xda  = (const float*)d_in[1];
    const int*   ei   = (const int*)d_in[2];
    const int*   batch= (const int*)d_in[3];
    const int*   root = (const int*)d_in[4];
    const float* W1   = (const float*)d_in[5];
    const float* b1   = (const float*)d_in[6];
    const float* W2   = (const float*)d_in[7];
    const float* b2   = (const float*)d_in[8];
    float* out = (float*)d_out;

    int N = in_sizes[3];
    int E = in_sizes[2] / 2;
    int B = in_sizes[4];

    int gN   = (N + 255) / 256;
    int gE   = (E + 255) / 256;
    int gN16 = (N * 16 + 255) / 256;
    int gM   = (N + 63) / 64;
    int nb   = gN;

    auto align = [](size_t v) { return (v + 255) & ~(size_t)255; };
    char* w = (char*)d_ws;
    float* dinv   = (float*)w;  w += align((size_t)N * 4);
    int*   counts = (int*)w;    w += align((size_t)N * 4);
    int*   rowst  = (int*)w;    w += align((size_t)(N + 1) * 4);
    int*   bsum   = (int*)w;    w += align((size_t)nb * 4);
    int*   boff   = (int*)w;    w += align((size_t)nb * 4);
    int*   csr_src= (int*)w;    w += align((size_t)E * 4);
    float* csr_w  = (float*)w;  w += align((size_t)E * 4);
    float* bufA   = (float*)w;  w += align((size_t)N * HID * 4);   // h1 then h2lin
    float* bufB   = (float*)w;  w += align((size_t)N * HID * 4);   // x2
    float* bufC   = (float*)w;  w += align((size_t)N * HID * 4);   // conv2 pre-relu
    float* rb2    = (float*)w;  w += align((size_t)B * HID * 4);
    int*   segs   = (int*)w;    w += align((size_t)(B + 1) * 4);
    __bf16* w1img = (__bf16*)w; w += align((size_t)64 * K1 * 2);
    __bf16* w2img = (__bf16*)w; w += align((size_t)64 * 64 * 2);
    float* part   = (float*)w;  w += align((size_t)B * MCH * 64 * 4);

    // ---- CSR build + dinv + prep (independent of GEMMs) ----
    zero_counts<<<gN, 256, 0, stream>>>(counts, N);
    count_edges<<<gE, 256, 0, stream>>>(ei, counts, E);
    dinv_k<<<gN, 256, 0, stream>>>(counts, dinv, N);
    block_sums<<<gN, 256, 0, stream>>>(counts, bsum, N);
    scan_bsums<<<1, 512, 0, stream>>>(bsum, boff, nb);
    write_rowstart<<<gN, 256, 0, stream>>>(counts, boff, rowst, N, E);
    scatter_csr<<<gE, 256, 0, stream>>>(ei, rowst, dinv, counts, csr_src, csr_w, E);
    seg_bounds<<<1, 256, 0, stream>>>(batch, segs, N, B);
    prep_w<<<(64 * K1 + 64 * 64 + 255) / 256, 256, 0, stream>>>(W1, W2, w1img, w2img);
    rb2_k<<<B, 64, 0, stream>>>(x, xda, root, W2, rb2);

    // ---- layer 1 ----
    gemm1_mfma<<<gM, 256, 0, stream>>>(x, xda, w1img, bufA, N);
    gather<<<gN16, 256, 0, stream>>>(rowst, csr_src, csr_w, bufA, dinv, b1, bufB, N);  // bufB = x2

    // ---- layer 2 ----
    gemm2_mfma<<<gM, 256, 0, stream>>>(bufB, w2img, rb2, batch, bufA, N);              // bufA = h2lin
    gather<<<gN16, 256, 0, stream>>>(rowst, csr_src, csr_w, bufA, dinv, b2, bufC, N);

    // ---- readout ----
    mean_part<<<B * MCH, 256, 0, stream>>>(bufC, segs, part);
    mean_fin<<<B, 128, 0, stream>>>(part, bufB, segs, root, out);
}